// Round 3
// baseline (376.634 us; speedup 1.0000x reference)
//
#include <hip/hip_runtime.h>

// ---------------------------------------------------------------------------
// TransD-style scoring:
//   score[b] = || rp*(hp.h) + sum(h) + r - rp*(tp.t) - sum(t) ||^2
// Algebraic reduction: with a = hp.h - tp.t, c = sum(h) - sum(t):
//   score = a^2*S_pp + c^2*D + S_rr + 2ac*S_p + 2a*S_pr + 2c*S_r
// Pass 1: per-node (sum, dot). Pass 2: per-relation sums. Pass 3: O(1) score.
// ---------------------------------------------------------------------------

#define ENT_DIM 128

// Pass 1: per-node (sum, dot) for head and tail tables.
// PERSISTENT grid-stride version of the round-0 structure: one wave covers 2
// rows per step (lanes 0-31 -> row 2p, lanes 32-63 -> row 2p+1; float4 loads,
// 2 contiguous 512B segments per instruction), but each wave now loops over
// many row-pairs, unrolled x4 with all 16 loads batched before consumption.
// Goal: keep every wave slot continuously issuing loads (m13 copy-bench
// structure) instead of 200k one-shot waves with idle reduce/retire tails.
__global__ void node_stats_kernel(const float* __restrict__ he,
                                  const float* __restrict__ hep,
                                  const float* __restrict__ te,
                                  const float* __restrict__ tep,
                                  float2* __restrict__ hstats,
                                  float2* __restrict__ tstats,
                                  int n_nodes) {
    const int lane   = threadIdx.x & 63;
    const int half   = lane >> 5;     // which of the 2 rows this lane serves
    const int l      = lane & 31;     // float4 index within the row
    const int wave   = (blockIdx.x * blockDim.x + threadIdx.x) >> 6;
    const int nwaves = (gridDim.x * blockDim.x) >> 6;
    const int npairs = n_nodes;       // job pairs; jobs = 2*n_nodes rows total

    int p = wave;
    for (; p + 3 * nwaves < npairs; p += 4 * nwaves) {
        float4 v[4], vp[4];
        float2* stp[4];
        int nd[4];
        // Batch all 16 loads (8 instructions, each 2x512B contiguous) before
        // any consumption -> deep MLP per wave slot.
        #pragma unroll
        for (int k = 0; k < 4; ++k) {
            const int job = 2 * (p + k * nwaves) + half;
            const float* emb; const float* embp;
            if (job < n_nodes) { emb = he; embp = hep; stp[k] = hstats; nd[k] = job; }
            else               { emb = te; embp = tep; stp[k] = tstats; nd[k] = job - n_nodes; }
            v[k]  = ((const float4*)(emb  + (size_t)nd[k] * ENT_DIM))[l];
            vp[k] = ((const float4*)(embp + (size_t)nd[k] * ENT_DIM))[l];
        }
        // Consume in order: reduce for segment k overlaps in-flight loads k+1..3.
        #pragma unroll
        for (int k = 0; k < 4; ++k) {
            float s = (v[k].x + v[k].y) + (v[k].z + v[k].w);
            float d = v[k].x * vp[k].x + v[k].y * vp[k].y
                    + v[k].z * vp[k].z + v[k].w * vp[k].w;
            #pragma unroll
            for (int off = 16; off >= 1; off >>= 1) {
                s += __shfl_xor(s, off, 64);
                d += __shfl_xor(d, off, 64);
            }
            if (l == 0) stp[k][nd[k]] = make_float2(s, d);
        }
    }
    // Remainder pairs.
    for (; p < npairs; p += nwaves) {
        const int job = 2 * p + half;
        const float* emb; const float* embp; float2* st; int node;
        if (job < n_nodes) { emb = he; embp = hep; st = hstats; node = job; }
        else               { emb = te; embp = tep; st = tstats; node = job - n_nodes; }
        const float4 v  = ((const float4*)(emb  + (size_t)node * ENT_DIM))[l];
        const float4 w  = ((const float4*)(embp + (size_t)node * ENT_DIM))[l];
        float s = (v.x + v.y) + (v.z + v.w);
        float d = v.x * w.x + v.y * w.y + v.z * w.z + v.w * w.w;
        #pragma unroll
        for (int off = 16; off >= 1; off >>= 1) {
            s += __shfl_xor(s, off, 64);
            d += __shfl_xor(d, off, 64);
        }
        if (l == 0) st[node] = make_float2(s, d);
    }
}

// Pass 2: per-relation sums. One wave per relation (only 500).
__global__ void rel_stats_kernel(const float* __restrict__ re,
                                 const float* __restrict__ rep,
                                 float* __restrict__ rstats, int n_rels) {
    const int wave = (blockIdx.x * blockDim.x + threadIdx.x) >> 6;
    const int lane = threadIdx.x & 63;
    if (wave >= n_rels) return;

    const float2 r = ((const float2*)(re  + (size_t)wave * ENT_DIM))[lane];
    const float2 p = ((const float2*)(rep + (size_t)wave * ENT_DIM))[lane];
    float s_pp = p.x * p.x + p.y * p.y;
    float s_p  = p.x + p.y;
    float s_pr = p.x * r.x + p.y * r.y;
    float s_r  = r.x + r.y;
    float s_rr = r.x * r.x + r.y * r.y;
    #pragma unroll
    for (int off = 32; off >= 1; off >>= 1) {
        s_pp += __shfl_xor(s_pp, off, 64);
        s_p  += __shfl_xor(s_p,  off, 64);
        s_pr += __shfl_xor(s_pr, off, 64);
        s_r  += __shfl_xor(s_r,  off, 64);
        s_rr += __shfl_xor(s_rr, off, 64);
    }
    if (lane == 0) {
        float* o = rstats + (size_t)wave * 8;   // 32B stride per relation
        o[0] = s_pp; o[1] = s_p; o[2] = s_pr; o[3] = s_r; o[4] = s_rr;
    }
}

// Pass 3: 2 batch elements per thread; idx loads int2-vectorized; rstats in
// LDS with stride-9 padding (random ri covers all 32 banks); 4 independent
// L2-resident 8B gathers in flight per thread.
__global__ void score_kernel(const int* __restrict__ hidx,
                             const int* __restrict__ tidx,
                             const int* __restrict__ ridx,
                             const float2* __restrict__ hstats,
                             const float2* __restrict__ tstats,
                             const float* __restrict__ rstats,
                             float* __restrict__ out, int B, int n_rels) {
    extern __shared__ float rs[];   // n_rels * 9 floats
    for (int i = threadIdx.x; i < n_rels * 2; i += blockDim.x) {
        const float4 v = ((const float4*)rstats)[i];
        const int base = (i >> 1) * 9 + (i & 1) * 4;
        rs[base]     = v.x;
        rs[base + 1] = v.y;
        rs[base + 2] = v.z;
        rs[base + 3] = v.w;
    }
    __syncthreads();

    const int g  = blockIdx.x * blockDim.x + threadIdx.x;
    const int b0 = 2 * g;
    if (b0 >= B) return;

    if (b0 + 1 < B) {
        const int2 hi = ((const int2*)hidx)[g];
        const int2 ti = ((const int2*)tidx)[g];
        const int2 ri = ((const int2*)ridx)[g];
        const float2 hs0 = hstats[hi.x];
        const float2 hs1 = hstats[hi.y];
        const float2 ts0 = tstats[ti.x];
        const float2 ts1 = tstats[ti.y];

        const float c0 = hs0.x - ts0.x, a0 = hs0.y - ts0.y;
        const float c1 = hs1.x - ts1.x, a1 = hs1.y - ts1.y;
        const float* q0 = rs + ri.x * 9;
        const float* q1 = rs + ri.y * 9;
        const float sc0 = a0 * a0 * q0[0] + c0 * c0 * (float)ENT_DIM + q0[4]
                        + 2.0f * (a0 * c0 * q0[1] + a0 * q0[2] + c0 * q0[3]);
        const float sc1 = a1 * a1 * q1[0] + c1 * c1 * (float)ENT_DIM + q1[4]
                        + 2.0f * (a1 * c1 * q1[1] + a1 * q1[2] + c1 * q1[3]);
        ((float2*)out)[g] = make_float2(sc0, sc1);
    } else {
        const int hi = hidx[b0], ti = tidx[b0], ri = ridx[b0];
        const float2 hs = hstats[hi];
        const float2 ts = tstats[ti];
        const float c = hs.x - ts.x, a = hs.y - ts.y;
        const float* q = rs + ri * 9;
        out[b0] = a * a * q[0] + c * c * (float)ENT_DIM + q[4]
                + 2.0f * (a * c * q[1] + a * q[2] + c * q[3]);
    }
}

// Fallback (only if ws_size is too small): direct wave-per-element compute.
__global__ void direct_kernel(const float* __restrict__ he, const float* __restrict__ hep,
                              const float* __restrict__ te, const float* __restrict__ tep,
                              const float* __restrict__ re, const float* __restrict__ rep,
                              const int* __restrict__ hidx, const int* __restrict__ tidx,
                              const int* __restrict__ ridx,
                              float* __restrict__ out, int B) {
    const int wave = (blockIdx.x * blockDim.x + threadIdx.x) >> 6;
    const int lane = threadIdx.x & 63;
    if (wave >= B) return;
    const int hi = hidx[wave], ti = tidx[wave], ri = ridx[wave];
    const float2 h  = ((const float2*)(he  + (size_t)hi * ENT_DIM))[lane];
    const float2 hp = ((const float2*)(hep + (size_t)hi * ENT_DIM))[lane];
    const float2 t  = ((const float2*)(te  + (size_t)ti * ENT_DIM))[lane];
    const float2 tp = ((const float2*)(tep + (size_t)ti * ENT_DIM))[lane];
    const float2 r  = ((const float2*)(re  + (size_t)ri * ENT_DIM))[lane];
    const float2 rp = ((const float2*)(rep + (size_t)ri * ENT_DIM))[lane];
    float hd = h.x * hp.x + h.y * hp.y;
    float hs = h.x + h.y;
    float td = t.x * tp.x + t.y * tp.y;
    float ts = t.x + t.y;
    #pragma unroll
    for (int off = 32; off >= 1; off >>= 1) {
        hd += __shfl_xor(hd, off, 64);
        hs += __shfl_xor(hs, off, 64);
        td += __shfl_xor(td, off, 64);
        ts += __shfl_xor(ts, off, 64);
    }
    const float a = hd - td, c = hs - ts;
    const float dx = a * rp.x + c + r.x;
    const float dy = a * rp.y + c + r.y;
    float sc = dx * dx + dy * dy;
    #pragma unroll
    for (int off = 32; off >= 1; off >>= 1) sc += __shfl_xor(sc, off, 64);
    if (lane == 0) out[wave] = sc;
}

extern "C" void kernel_launch(void* const* d_in, const int* in_sizes, int n_in,
                              void* d_out, int out_size, void* d_ws, size_t ws_size,
                              hipStream_t stream) {
    const float* he  = (const float*)d_in[0];
    const float* hep = (const float*)d_in[1];
    const float* te  = (const float*)d_in[2];
    const float* tep = (const float*)d_in[3];
    const float* re  = (const float*)d_in[4];
    const float* rep = (const float*)d_in[5];
    const int* hidx  = (const int*)d_in[6];
    const int* tidx  = (const int*)d_in[7];
    const int* ridx  = (const int*)d_in[8];
    float* out = (float*)d_out;

    const int n_nodes = in_sizes[0] / ENT_DIM;   // 200000
    const int n_rels  = in_sizes[4] / ENT_DIM;   // 500
    const int B       = in_sizes[6];             // 500000

    const size_t hstats_bytes = (size_t)n_nodes * sizeof(float2);
    const size_t rstats_bytes = (size_t)n_rels * 8 * sizeof(float);
    const size_t need = 2 * hstats_bytes + rstats_bytes;
    const size_t lds_bytes = (size_t)n_rels * 9 * sizeof(float);

    if (ws_size >= need && lds_bytes <= 60 * 1024) {
        float2* hstats = (float2*)d_ws;
        float2* tstats = (float2*)((char*)d_ws + hstats_bytes);
        float*  rstats = (float*)((char*)d_ws + 2 * hstats_bytes);

        // Pass 1: persistent grid — 2048 blocks x 256 thr = 8192 waves
        // (8 blocks/CU, full 32 waves/CU), each wave loops ~12 row-pairs.
        const int npairs  = n_nodes;
        int blocks1 = (npairs + 3) / 4;           // at most 1 pair per wave per unroll step
        if (blocks1 > 2048) blocks1 = 2048;
        node_stats_kernel<<<blocks1, 256, 0, stream>>>(he, hep, te, tep,
                                                       hstats, tstats, n_nodes);
        // Pass 2
        const int blocks2 = (n_rels * 64 + 255) / 256;
        rel_stats_kernel<<<blocks2, 256, 0, stream>>>(re, rep, rstats, n_rels);
        // Pass 3: 2 elements per thread.
        const int nthreads = (B + 1) / 2;
        const int blocks3  = (nthreads + 255) / 256;
        score_kernel<<<blocks3, 256, lds_bytes, stream>>>(hidx, tidx, ridx,
                                                          hstats, tstats, rstats,
                                                          out, B, n_rels);
    } else {
        const int blocks = (B * 64 + 255) / 256;
        direct_kernel<<<blocks, 256, 0, stream>>>(he, hep, te, tep, re, rep,
                                                  hidx, tidx, ridx, out, B);
    }
}

// Round 4
// 356.864 us; speedup vs baseline: 1.0554x; 1.0554x over previous
//
#include <hip/hip_runtime.h>

// ---------------------------------------------------------------------------
// TransD-style scoring:
//   score[b] = || rp*(hp.h) + sum(h) + r - rp*(tp.t) - sum(t) ||^2
// Algebraic reduction: with a = hp.h - tp.t, c = sum(h) - sum(t):
//   score = a^2*S_pp + c^2*D + S_rr + 2ac*S_p + 2a*S_pr + 2c*S_r
// Pass 1: per-node (sum, dot). Pass 2: per-relation sums. Pass 3: O(1) score.
// ---------------------------------------------------------------------------

#define ENT_DIM 128

// Pass 1: per-node (sum, dot) for head and tail tables.
// v4: one-shot waves (persistence regressed in R3), but each wave now owns
// 4 CONSECUTIVE rows (2 KB contiguous per table, vs R0's 1 KB) with all 8
// float4 loads batched before any reduce. 512-thread blocks -> one block
// covers 32 consecutive rows (16 KB contiguous per table). Reduce = 4
// independent 5-step xor chains (ILP in the DS pipe). VGPR ~32 ->
// __launch_bounds__(512,8) keeps 100% occupancy.
__global__ __launch_bounds__(512, 8)
void node_stats_kernel(const float* __restrict__ he,
                       const float* __restrict__ hep,
                       const float* __restrict__ te,
                       const float* __restrict__ tep,
                       float2* __restrict__ hstats,
                       float2* __restrict__ tstats,
                       int n_nodes) {
    const int lane  = threadIdx.x & 63;
    const int half  = lane >> 5;      // row within a pair
    const int l     = lane & 31;      // float4 slot within the row
    const int wave  = (blockIdx.x * blockDim.x + threadIdx.x) >> 6;
    const int njobs = 2 * n_nodes;    // head rows then tail rows
    const int j0    = wave * 4;       // 4 consecutive jobs per wave
    if (j0 >= njobs) return;

    if (j0 + 3 < njobs) {
        float4 v[2], p[2];
        float2* st[2];
        int nd[2];
        // Batch all 8 loads (4 instructions, each 2x512B contiguous; the
        // wave's total footprint is 2KB contiguous per table).
        #pragma unroll
        for (int k = 0; k < 2; ++k) {
            const int job = j0 + 2 * k + half;
            const float* emb; const float* embp;
            if (job < n_nodes) { emb = he; embp = hep; st[k] = hstats; nd[k] = job; }
            else               { emb = te; embp = tep; st[k] = tstats; nd[k] = job - n_nodes; }
            v[k] = ((const float4*)(emb  + (size_t)nd[k] * ENT_DIM))[l];
            p[k] = ((const float4*)(embp + (size_t)nd[k] * ENT_DIM))[l];
        }
        float s0 = (v[0].x + v[0].y) + (v[0].z + v[0].w);
        float d0 = v[0].x * p[0].x + v[0].y * p[0].y + v[0].z * p[0].z + v[0].w * p[0].w;
        float s1 = (v[1].x + v[1].y) + (v[1].z + v[1].w);
        float d1 = v[1].x * p[1].x + v[1].y * p[1].y + v[1].z * p[1].z + v[1].w * p[1].w;
        // 4 independent chains -> shuffle latency overlaps.
        #pragma unroll
        for (int off = 16; off >= 1; off >>= 1) {
            s0 += __shfl_xor(s0, off, 64);
            d0 += __shfl_xor(d0, off, 64);
            s1 += __shfl_xor(s1, off, 64);
            d1 += __shfl_xor(d1, off, 64);
        }
        if (l == 0) {
            st[0][nd[0]] = make_float2(s0, d0);
            st[1][nd[1]] = make_float2(s1, d1);
        }
    } else {
        // Tail: process remaining pairs one at a time (R0 body).
        #pragma unroll
        for (int k = 0; k < 2; ++k) {
            const int job = j0 + 2 * k + half;
            if (job >= njobs) continue;
            const float* emb; const float* embp; float2* st; int node;
            if (job < n_nodes) { emb = he; embp = hep; st = hstats; node = job; }
            else               { emb = te; embp = tep; st = tstats; node = job - n_nodes; }
            const float4 v = ((const float4*)(emb  + (size_t)node * ENT_DIM))[l];
            const float4 w = ((const float4*)(embp + (size_t)node * ENT_DIM))[l];
            float s = (v.x + v.y) + (v.z + v.w);
            float d = v.x * w.x + v.y * w.y + v.z * w.z + v.w * w.w;
            #pragma unroll
            for (int off = 16; off >= 1; off >>= 1) {
                s += __shfl_xor(s, off, 64);
                d += __shfl_xor(d, off, 64);
            }
            if (l == 0) st[node] = make_float2(s, d);
        }
    }
}

// Pass 2: per-relation sums. One wave per relation (only 500).
__global__ void rel_stats_kernel(const float* __restrict__ re,
                                 const float* __restrict__ rep,
                                 float* __restrict__ rstats, int n_rels) {
    const int wave = (blockIdx.x * blockDim.x + threadIdx.x) >> 6;
    const int lane = threadIdx.x & 63;
    if (wave >= n_rels) return;

    const float2 r = ((const float2*)(re  + (size_t)wave * ENT_DIM))[lane];
    const float2 p = ((const float2*)(rep + (size_t)wave * ENT_DIM))[lane];
    float s_pp = p.x * p.x + p.y * p.y;
    float s_p  = p.x + p.y;
    float s_pr = p.x * r.x + p.y * r.y;
    float s_r  = r.x + r.y;
    float s_rr = r.x * r.x + r.y * r.y;
    #pragma unroll
    for (int off = 32; off >= 1; off >>= 1) {
        s_pp += __shfl_xor(s_pp, off, 64);
        s_p  += __shfl_xor(s_p,  off, 64);
        s_pr += __shfl_xor(s_pr, off, 64);
        s_r  += __shfl_xor(s_r,  off, 64);
        s_rr += __shfl_xor(s_rr, off, 64);
    }
    if (lane == 0) {
        float* o = rstats + (size_t)wave * 8;   // 32B stride per relation
        o[0] = s_pp; o[1] = s_p; o[2] = s_pr; o[3] = s_r; o[4] = s_rr;
    }
}

// Pass 3 (frozen at R2 config): 2 batch elements per thread; int2 idx loads;
// rstats in LDS stride-9 (random ri covers all 32 banks); 4 independent
// L2-resident 8B gathers in flight per thread.
__global__ void score_kernel(const int* __restrict__ hidx,
                             const int* __restrict__ tidx,
                             const int* __restrict__ ridx,
                             const float2* __restrict__ hstats,
                             const float2* __restrict__ tstats,
                             const float* __restrict__ rstats,
                             float* __restrict__ out, int B, int n_rels) {
    extern __shared__ float rs[];   // n_rels * 9 floats
    for (int i = threadIdx.x; i < n_rels * 2; i += blockDim.x) {
        const float4 v = ((const float4*)rstats)[i];
        const int base = (i >> 1) * 9 + (i & 1) * 4;
        rs[base]     = v.x;
        rs[base + 1] = v.y;
        rs[base + 2] = v.z;
        rs[base + 3] = v.w;
    }
    __syncthreads();

    const int g  = blockIdx.x * blockDim.x + threadIdx.x;
    const int b0 = 2 * g;
    if (b0 >= B) return;

    if (b0 + 1 < B) {
        const int2 hi = ((const int2*)hidx)[g];
        const int2 ti = ((const int2*)tidx)[g];
        const int2 ri = ((const int2*)ridx)[g];
        const float2 hs0 = hstats[hi.x];
        const float2 hs1 = hstats[hi.y];
        const float2 ts0 = tstats[ti.x];
        const float2 ts1 = tstats[ti.y];

        const float c0 = hs0.x - ts0.x, a0 = hs0.y - ts0.y;
        const float c1 = hs1.x - ts1.x, a1 = hs1.y - ts1.y;
        const float* q0 = rs + ri.x * 9;
        const float* q1 = rs + ri.y * 9;
        const float sc0 = a0 * a0 * q0[0] + c0 * c0 * (float)ENT_DIM + q0[4]
                        + 2.0f * (a0 * c0 * q0[1] + a0 * q0[2] + c0 * q0[3]);
        const float sc1 = a1 * a1 * q1[0] + c1 * c1 * (float)ENT_DIM + q1[4]
                        + 2.0f * (a1 * c1 * q1[1] + a1 * q1[2] + c1 * q1[3]);
        ((float2*)out)[g] = make_float2(sc0, sc1);
    } else {
        const int hi = hidx[b0], ti = tidx[b0], ri = ridx[b0];
        const float2 hs = hstats[hi];
        const float2 ts = tstats[ti];
        const float c = hs.x - ts.x, a = hs.y - ts.y;
        const float* q = rs + ri * 9;
        out[b0] = a * a * q[0] + c * c * (float)ENT_DIM + q[4]
                + 2.0f * (a * c * q[1] + a * q[2] + c * q[3]);
    }
}

// Fallback (only if ws_size is too small): direct wave-per-element compute.
__global__ void direct_kernel(const float* __restrict__ he, const float* __restrict__ hep,
                              const float* __restrict__ te, const float* __restrict__ tep,
                              const float* __restrict__ re, const float* __restrict__ rep,
                              const int* __restrict__ hidx, const int* __restrict__ tidx,
                              const int* __restrict__ ridx,
                              float* __restrict__ out, int B) {
    const int wave = (blockIdx.x * blockDim.x + threadIdx.x) >> 6;
    const int lane = threadIdx.x & 63;
    if (wave >= B) return;
    const int hi = hidx[wave], ti = tidx[wave], ri = ridx[wave];
    const float2 h  = ((const float2*)(he  + (size_t)hi * ENT_DIM))[lane];
    const float2 hp = ((const float2*)(hep + (size_t)hi * ENT_DIM))[lane];
    const float2 t  = ((const float2*)(te  + (size_t)ti * ENT_DIM))[lane];
    const float2 tp = ((const float2*)(tep + (size_t)ti * ENT_DIM))[lane];
    const float2 r  = ((const float2*)(re  + (size_t)ri * ENT_DIM))[lane];
    const float2 rp = ((const float2*)(rep + (size_t)ri * ENT_DIM))[lane];
    float hd = h.x * hp.x + h.y * hp.y;
    float hs = h.x + h.y;
    float td = t.x * tp.x + t.y * tp.y;
    float ts = t.x + t.y;
    #pragma unroll
    for (int off = 32; off >= 1; off >>= 1) {
        hd += __shfl_xor(hd, off, 64);
        hs += __shfl_xor(hs, off, 64);
        td += __shfl_xor(td, off, 64);
        ts += __shfl_xor(ts, off, 64);
    }
    const float a = hd - td, c = hs - ts;
    const float dx = a * rp.x + c + r.x;
    const float dy = a * rp.y + c + r.y;
    float sc = dx * dx + dy * dy;
    #pragma unroll
    for (int off = 32; off >= 1; off >>= 1) sc += __shfl_xor(sc, off, 64);
    if (lane == 0) out[wave] = sc;
}

extern "C" void kernel_launch(void* const* d_in, const int* in_sizes, int n_in,
                              void* d_out, int out_size, void* d_ws, size_t ws_size,
                              hipStream_t stream) {
    const float* he  = (const float*)d_in[0];
    const float* hep = (const float*)d_in[1];
    const float* te  = (const float*)d_in[2];
    const float* tep = (const float*)d_in[3];
    const float* re  = (const float*)d_in[4];
    const float* rep = (const float*)d_in[5];
    const int* hidx  = (const int*)d_in[6];
    const int* tidx  = (const int*)d_in[7];
    const int* ridx  = (const int*)d_in[8];
    float* out = (float*)d_out;

    const int n_nodes = in_sizes[0] / ENT_DIM;   // 200000
    const int n_rels  = in_sizes[4] / ENT_DIM;   // 500
    const int B       = in_sizes[6];             // 500000

    const size_t hstats_bytes = (size_t)n_nodes * sizeof(float2);
    const size_t rstats_bytes = (size_t)n_rels * 8 * sizeof(float);
    const size_t need = 2 * hstats_bytes + rstats_bytes;
    const size_t lds_bytes = (size_t)n_rels * 9 * sizeof(float);

    if (ws_size >= need && lds_bytes <= 60 * 1024) {
        float2* hstats = (float2*)d_ws;
        float2* tstats = (float2*)((char*)d_ws + hstats_bytes);
        float*  rstats = (float*)((char*)d_ws + 2 * hstats_bytes);

        // Pass 1: 2*n_nodes rows, 4 rows/wave, 8 waves/block (512 thr).
        const int njobs   = 2 * n_nodes;
        const int waves1  = (njobs + 3) / 4;
        const int blocks1 = (waves1 + 7) / 8;
        node_stats_kernel<<<blocks1, 512, 0, stream>>>(he, hep, te, tep,
                                                       hstats, tstats, n_nodes);
        // Pass 2
        const int blocks2 = (n_rels * 64 + 255) / 256;
        rel_stats_kernel<<<blocks2, 256, 0, stream>>>(re, rep, rstats, n_rels);
        // Pass 3: 2 elements per thread.
        const int nthreads = (B + 1) / 2;
        const int blocks3  = (nthreads + 255) / 256;
        score_kernel<<<blocks3, 256, lds_bytes, stream>>>(hidx, tidx, ridx,
                                                          hstats, tstats, rstats,
                                                          out, B, n_rels);
    } else {
        const int blocks = (B * 64 + 255) / 256;
        direct_kernel<<<blocks, 256, 0, stream>>>(he, hep, te, tep, re, rep,
                                                  hidx, tidx, ridx, out, B);
    }
}

// Round 5
// 344.258 us; speedup vs baseline: 1.0940x; 1.0366x over previous
//
#include <hip/hip_runtime.h>

// ---------------------------------------------------------------------------
// TransD-style scoring:
//   score[b] = || rp*(hp.h) + sum(h) + r - rp*(tp.t) - sum(t) ||^2
// Algebraic reduction: with a = hp.h - tp.t, c = sum(h) - sum(t):
//   score = a^2*S_pp + c^2*D + S_rr + 2ac*S_p + 2a*S_pr + 2c*S_r
// Pass 1: per-node (sum, dot). Pass 2: per-relation sums. Pass 3: O(1) score.
//
// R5 experiment: deterministic Infinity-Cache partitioning. he/hep (204.8 MB)
// are loaded normally -> converge to full IC residency. te/tep are loaded
// NON-TEMPORAL (no-allocate) -> pure HBM stream that does not evict he/hep.
// Two disjoint overlapping streams instead of a random 50/50 hit/miss mix.
// ---------------------------------------------------------------------------

#define ENT_DIM 128

typedef float f4_t __attribute__((ext_vector_type(4)));

__device__ __forceinline__ float4 ldg_nt4(const float* p) {
    f4_t v = __builtin_nontemporal_load((const f4_t*)p);
    return make_float4(v.x, v.y, v.z, v.w);
}

// Pass 1: per-node (sum, dot) for head and tail tables.
// R0 structure (measured fastest of 4 variants): one wave handles 2 rows,
// lanes 0-31 -> row 2w, lanes 32-63 -> row 2w+1; float4 loads, 2 contiguous
// 512B segments per instruction. Branch on head/tail is wave-uniform.
__global__ void node_stats_kernel(const float* __restrict__ he,
                                  const float* __restrict__ hep,
                                  const float* __restrict__ te,
                                  const float* __restrict__ tep,
                                  float2* __restrict__ hstats,
                                  float2* __restrict__ tstats,
                                  int n_nodes) {
    const int wave  = (blockIdx.x * blockDim.x + threadIdx.x) >> 6;
    const int lane  = threadIdx.x & 63;
    const int half  = lane >> 5;      // which of the 2 rows this lane serves
    const int l     = lane & 31;      // float4 index within the row
    const int njobs = 2 * n_nodes;    // head rows then tail rows

    const int job = wave * 2 + half;
    if (job >= njobs) return;

    float4 v, vp;
    float2* st;
    int node;
    if (job < n_nodes) {
        // Head tables: normal loads -> allocate in IC (204.8 MB fits).
        node = job;
        st = hstats;
        v  = ((const float4*)(he  + (size_t)node * ENT_DIM))[l];
        vp = ((const float4*)(hep + (size_t)node * ENT_DIM))[l];
    } else {
        // Tail tables: non-temporal stream -> bypass cache allocation,
        // leave IC to the head tables.
        node = job - n_nodes;
        st = tstats;
        v  = ldg_nt4(te  + (size_t)node * ENT_DIM + 4 * l);
        vp = ldg_nt4(tep + (size_t)node * ENT_DIM + 4 * l);
    }

    float s = (v.x + v.y) + (v.z + v.w);
    float d = v.x * vp.x + v.y * vp.y + v.z * vp.z + v.w * vp.w;

    // reduce within each 32-lane half (xor masks < 32 never cross halves)
    #pragma unroll
    for (int off = 16; off >= 1; off >>= 1) {
        s += __shfl_xor(s, off, 64);
        d += __shfl_xor(d, off, 64);
    }
    if (l == 0) st[node] = make_float2(s, d);
}

// Pass 2: per-relation sums. One wave per relation (only 500).
__global__ void rel_stats_kernel(const float* __restrict__ re,
                                 const float* __restrict__ rep,
                                 float* __restrict__ rstats, int n_rels) {
    const int wave = (blockIdx.x * blockDim.x + threadIdx.x) >> 6;
    const int lane = threadIdx.x & 63;
    if (wave >= n_rels) return;

    const float2 r = ((const float2*)(re  + (size_t)wave * ENT_DIM))[lane];
    const float2 p = ((const float2*)(rep + (size_t)wave * ENT_DIM))[lane];
    float s_pp = p.x * p.x + p.y * p.y;
    float s_p  = p.x + p.y;
    float s_pr = p.x * r.x + p.y * r.y;
    float s_r  = r.x + r.y;
    float s_rr = r.x * r.x + r.y * r.y;
    #pragma unroll
    for (int off = 32; off >= 1; off >>= 1) {
        s_pp += __shfl_xor(s_pp, off, 64);
        s_p  += __shfl_xor(s_p,  off, 64);
        s_pr += __shfl_xor(s_pr, off, 64);
        s_r  += __shfl_xor(s_r,  off, 64);
        s_rr += __shfl_xor(s_rr, off, 64);
    }
    if (lane == 0) {
        float* o = rstats + (size_t)wave * 8;   // 32B stride per relation
        o[0] = s_pp; o[1] = s_p; o[2] = s_pr; o[3] = s_r; o[4] = s_rr;
    }
}

// Pass 3 (frozen at R2 config): 2 batch elements per thread; int2 idx loads;
// rstats in LDS stride-9 (random ri covers all 32 banks); 4 independent
// L2-resident 8B gathers in flight per thread.
__global__ void score_kernel(const int* __restrict__ hidx,
                             const int* __restrict__ tidx,
                             const int* __restrict__ ridx,
                             const float2* __restrict__ hstats,
                             const float2* __restrict__ tstats,
                             const float* __restrict__ rstats,
                             float* __restrict__ out, int B, int n_rels) {
    extern __shared__ float rs[];   // n_rels * 9 floats
    for (int i = threadIdx.x; i < n_rels * 2; i += blockDim.x) {
        const float4 v = ((const float4*)rstats)[i];
        const int base = (i >> 1) * 9 + (i & 1) * 4;
        rs[base]     = v.x;
        rs[base + 1] = v.y;
        rs[base + 2] = v.z;
        rs[base + 3] = v.w;
    }
    __syncthreads();

    const int g  = blockIdx.x * blockDim.x + threadIdx.x;
    const int b0 = 2 * g;
    if (b0 >= B) return;

    if (b0 + 1 < B) {
        const int2 hi = ((const int2*)hidx)[g];
        const int2 ti = ((const int2*)tidx)[g];
        const int2 ri = ((const int2*)ridx)[g];
        const float2 hs0 = hstats[hi.x];
        const float2 hs1 = hstats[hi.y];
        const float2 ts0 = tstats[ti.x];
        const float2 ts1 = tstats[ti.y];

        const float c0 = hs0.x - ts0.x, a0 = hs0.y - ts0.y;
        const float c1 = hs1.x - ts1.x, a1 = hs1.y - ts1.y;
        const float* q0 = rs + ri.x * 9;
        const float* q1 = rs + ri.y * 9;
        const float sc0 = a0 * a0 * q0[0] + c0 * c0 * (float)ENT_DIM + q0[4]
                        + 2.0f * (a0 * c0 * q0[1] + a0 * q0[2] + c0 * q0[3]);
        const float sc1 = a1 * a1 * q1[0] + c1 * c1 * (float)ENT_DIM + q1[4]
                        + 2.0f * (a1 * c1 * q1[1] + a1 * q1[2] + c1 * q1[3]);
        ((float2*)out)[g] = make_float2(sc0, sc1);
    } else {
        const int hi = hidx[b0], ti = tidx[b0], ri = ridx[b0];
        const float2 hs = hstats[hi];
        const float2 ts = tstats[ti];
        const float c = hs.x - ts.x, a = hs.y - ts.y;
        const float* q = rs + ri * 9;
        out[b0] = a * a * q[0] + c * c * (float)ENT_DIM + q[4]
                + 2.0f * (a * c * q[1] + a * q[2] + c * q[3]);
    }
}

// Fallback (only if ws_size is too small): direct wave-per-element compute.
__global__ void direct_kernel(const float* __restrict__ he, const float* __restrict__ hep,
                              const float* __restrict__ te, const float* __restrict__ tep,
                              const float* __restrict__ re, const float* __restrict__ rep,
                              const int* __restrict__ hidx, const int* __restrict__ tidx,
                              const int* __restrict__ ridx,
                              float* __restrict__ out, int B) {
    const int wave = (blockIdx.x * blockDim.x + threadIdx.x) >> 6;
    const int lane = threadIdx.x & 63;
    if (wave >= B) return;
    const int hi = hidx[wave], ti = tidx[wave], ri = ridx[wave];
    const float2 h  = ((const float2*)(he  + (size_t)hi * ENT_DIM))[lane];
    const float2 hp = ((const float2*)(hep + (size_t)hi * ENT_DIM))[lane];
    const float2 t  = ((const float2*)(te  + (size_t)ti * ENT_DIM))[lane];
    const float2 tp = ((const float2*)(tep + (size_t)ti * ENT_DIM))[lane];
    const float2 r  = ((const float2*)(re  + (size_t)ri * ENT_DIM))[lane];
    const float2 rp = ((const float2*)(rep + (size_t)ri * ENT_DIM))[lane];
    float hd = h.x * hp.x + h.y * hp.y;
    float hs = h.x + h.y;
    float td = t.x * tp.x + t.y * tp.y;
    float ts = t.x + t.y;
    #pragma unroll
    for (int off = 32; off >= 1; off >>= 1) {
        hd += __shfl_xor(hd, off, 64);
        hs += __shfl_xor(hs, off, 64);
        td += __shfl_xor(td, off, 64);
        ts += __shfl_xor(ts, off, 64);
    }
    const float a = hd - td, c = hs - ts;
    const float dx = a * rp.x + c + r.x;
    const float dy = a * rp.y + c + r.y;
    float sc = dx * dx + dy * dy;
    #pragma unroll
    for (int off = 32; off >= 1; off >>= 1) sc += __shfl_xor(sc, off, 64);
    if (lane == 0) out[wave] = sc;
}

extern "C" void kernel_launch(void* const* d_in, const int* in_sizes, int n_in,
                              void* d_out, int out_size, void* d_ws, size_t ws_size,
                              hipStream_t stream) {
    const float* he  = (const float*)d_in[0];
    const float* hep = (const float*)d_in[1];
    const float* te  = (const float*)d_in[2];
    const float* tep = (const float*)d_in[3];
    const float* re  = (const float*)d_in[4];
    const float* rep = (const float*)d_in[5];
    const int* hidx  = (const int*)d_in[6];
    const int* tidx  = (const int*)d_in[7];
    const int* ridx  = (const int*)d_in[8];
    float* out = (float*)d_out;

    const int n_nodes = in_sizes[0] / ENT_DIM;   // 200000
    const int n_rels  = in_sizes[4] / ENT_DIM;   // 500
    const int B       = in_sizes[6];             // 500000

    const size_t hstats_bytes = (size_t)n_nodes * sizeof(float2);
    const size_t rstats_bytes = (size_t)n_rels * 8 * sizeof(float);
    const size_t need = 2 * hstats_bytes + rstats_bytes;
    const size_t lds_bytes = (size_t)n_rels * 9 * sizeof(float);

    if (ws_size >= need && lds_bytes <= 60 * 1024) {
        float2* hstats = (float2*)d_ws;
        float2* tstats = (float2*)((char*)d_ws + hstats_bytes);
        float*  rstats = (float*)((char*)d_ws + 2 * hstats_bytes);

        // Pass 1: 2*n_nodes rows, 2 rows/wave, 4 waves/block.
        const int waves1  = n_nodes;                  // (2*n_nodes jobs)/2
        const int blocks1 = (waves1 + 3) / 4;
        node_stats_kernel<<<blocks1, 256, 0, stream>>>(he, hep, te, tep,
                                                       hstats, tstats, n_nodes);
        // Pass 2
        const int blocks2 = (n_rels * 64 + 255) / 256;
        rel_stats_kernel<<<blocks2, 256, 0, stream>>>(re, rep, rstats, n_rels);
        // Pass 3: 2 elements per thread.
        const int nthreads = (B + 1) / 2;
        const int blocks3  = (nthreads + 255) / 256;
        score_kernel<<<blocks3, 256, lds_bytes, stream>>>(hidx, tidx, ridx,
                                                          hstats, tstats, rstats,
                                                          out, B, n_rels);
    } else {
        const int blocks = (B * 64 + 255) / 256;
        direct_kernel<<<blocks, 256, 0, stream>>>(he, hep, te, tep, re, rep,
                                                  hidx, tidx, ridx, out, B);
    }
}

// Round 6
// 340.039 us; speedup vs baseline: 1.1076x; 1.0124x over previous
//
#include <hip/hip_runtime.h>

// ---------------------------------------------------------------------------
// TransD-style scoring:
//   score[b] = || rp*(hp.h) + sum(h) + r - rp*(tp.t) - sum(t) ||^2
// Algebraic reduction: with a = hp.h - tp.t, c = sum(h) - sum(t):
//   score = a^2*S_pp + c^2*D + S_rr + 2ac*S_p + 2a*S_pr + 2c*S_r
// Pass 1: per-node (sum, dot). Pass 2: per-relation sums. Pass 3: O(1) score.
//
// R5 (kept): deterministic IC partition — he/hep normal loads (IC-resident,
// confirmed: FETCH == te/tep footprint), te/tep non-temporal (HBM stream,
// no IC allocation).
// R6 (new): interleave head/tail pairs across ADJACENT waves so the IC
// stream and the HBM stream are concurrently resident instead of running
// as two sequential phases (R5 counters: combined 3.86 TB/s = serialized).
// ---------------------------------------------------------------------------

#define ENT_DIM 128

typedef float f4_t __attribute__((ext_vector_type(4)));

__device__ __forceinline__ float4 ldg_nt4(const float* p) {
    f4_t v = __builtin_nontemporal_load((const f4_t*)p);
    return make_float4(v.x, v.y, v.z, v.w);
}

// Pass 1: per-node (sum, dot) for head and tail tables.
// R0 body (fastest of 4 structures): one wave handles 2 rows, lanes 0-31 ->
// row 2p, lanes 32-63 -> row 2p+1; float4 loads, 2 contiguous 512B segments
// per instruction. NEW: pair index is a bijective even/odd permutation so
// even waves take head pairs, odd waves take tail pairs -> both memory
// paths active at every instant.
__global__ void node_stats_kernel(const float* __restrict__ he,
                                  const float* __restrict__ hep,
                                  const float* __restrict__ te,
                                  const float* __restrict__ tep,
                                  float2* __restrict__ hstats,
                                  float2* __restrict__ tstats,
                                  int n_nodes) {
    const int wave  = (blockIdx.x * blockDim.x + threadIdx.x) >> 6;
    const int lane  = threadIdx.x & 63;
    const int half  = lane >> 5;      // which of the 2 rows this lane serves
    const int l     = lane & 31;      // float4 index within the row
    const int npairs = n_nodes;       // 2*n_nodes rows / 2 rows per pair
    const int njobs  = 2 * n_nodes;

    if (wave >= npairs) return;
    // Bijective interleave: even wave -> pair wave/2 (front half = head rows),
    // odd wave -> pair ceil(npairs/2)+wave/2 (back half = tail rows).
    const int pair = (wave & 1) ? (((npairs + 1) >> 1) + (wave >> 1))
                                : (wave >> 1);
    const int job = pair * 2 + half;
    if (job >= njobs) return;

    float4 v, vp;
    float2* st;
    int node;
    if (job < n_nodes) {
        // Head tables: normal loads -> IC-resident (204.8 MB fits w/ slack).
        node = job;
        st = hstats;
        v  = ((const float4*)(he  + (size_t)node * ENT_DIM))[l];
        vp = ((const float4*)(hep + (size_t)node * ENT_DIM))[l];
    } else {
        // Tail tables: non-temporal -> pure HBM stream, no IC allocation.
        node = job - n_nodes;
        st = tstats;
        v  = ldg_nt4(te  + (size_t)node * ENT_DIM + 4 * l);
        vp = ldg_nt4(tep + (size_t)node * ENT_DIM + 4 * l);
    }

    float s = (v.x + v.y) + (v.z + v.w);
    float d = v.x * vp.x + v.y * vp.y + v.z * vp.z + v.w * vp.w;

    // reduce within each 32-lane half (xor masks < 32 never cross halves)
    #pragma unroll
    for (int off = 16; off >= 1; off >>= 1) {
        s += __shfl_xor(s, off, 64);
        d += __shfl_xor(d, off, 64);
    }
    if (l == 0) st[node] = make_float2(s, d);
}

// Pass 2: per-relation sums. One wave per relation (only 500).
__global__ void rel_stats_kernel(const float* __restrict__ re,
                                 const float* __restrict__ rep,
                                 float* __restrict__ rstats, int n_rels) {
    const int wave = (blockIdx.x * blockDim.x + threadIdx.x) >> 6;
    const int lane = threadIdx.x & 63;
    if (wave >= n_rels) return;

    const float2 r = ((const float2*)(re  + (size_t)wave * ENT_DIM))[lane];
    const float2 p = ((const float2*)(rep + (size_t)wave * ENT_DIM))[lane];
    float s_pp = p.x * p.x + p.y * p.y;
    float s_p  = p.x + p.y;
    float s_pr = p.x * r.x + p.y * r.y;
    float s_r  = r.x + r.y;
    float s_rr = r.x * r.x + r.y * r.y;
    #pragma unroll
    for (int off = 32; off >= 1; off >>= 1) {
        s_pp += __shfl_xor(s_pp, off, 64);
        s_p  += __shfl_xor(s_p,  off, 64);
        s_pr += __shfl_xor(s_pr, off, 64);
        s_r  += __shfl_xor(s_r,  off, 64);
        s_rr += __shfl_xor(s_rr, off, 64);
    }
    if (lane == 0) {
        float* o = rstats + (size_t)wave * 8;   // 32B stride per relation
        o[0] = s_pp; o[1] = s_p; o[2] = s_pr; o[3] = s_r; o[4] = s_rr;
    }
}

// Pass 3 (frozen at R2 config): 2 batch elements per thread; int2 idx loads;
// rstats in LDS stride-9 (random ri covers all 32 banks); 4 independent
// L2-resident 8B gathers in flight per thread.
__global__ void score_kernel(const int* __restrict__ hidx,
                             const int* __restrict__ tidx,
                             const int* __restrict__ ridx,
                             const float2* __restrict__ hstats,
                             const float2* __restrict__ tstats,
                             const float* __restrict__ rstats,
                             float* __restrict__ out, int B, int n_rels) {
    extern __shared__ float rs[];   // n_rels * 9 floats
    for (int i = threadIdx.x; i < n_rels * 2; i += blockDim.x) {
        const float4 v = ((const float4*)rstats)[i];
        const int base = (i >> 1) * 9 + (i & 1) * 4;
        rs[base]     = v.x;
        rs[base + 1] = v.y;
        rs[base + 2] = v.z;
        rs[base + 3] = v.w;
    }
    __syncthreads();

    const int g  = blockIdx.x * blockDim.x + threadIdx.x;
    const int b0 = 2 * g;
    if (b0 >= B) return;

    if (b0 + 1 < B) {
        const int2 hi = ((const int2*)hidx)[g];
        const int2 ti = ((const int2*)tidx)[g];
        const int2 ri = ((const int2*)ridx)[g];
        const float2 hs0 = hstats[hi.x];
        const float2 hs1 = hstats[hi.y];
        const float2 ts0 = tstats[ti.x];
        const float2 ts1 = tstats[ti.y];

        const float c0 = hs0.x - ts0.x, a0 = hs0.y - ts0.y;
        const float c1 = hs1.x - ts1.x, a1 = hs1.y - ts1.y;
        const float* q0 = rs + ri.x * 9;
        const float* q1 = rs + ri.y * 9;
        const float sc0 = a0 * a0 * q0[0] + c0 * c0 * (float)ENT_DIM + q0[4]
                        + 2.0f * (a0 * c0 * q0[1] + a0 * q0[2] + c0 * q0[3]);
        const float sc1 = a1 * a1 * q1[0] + c1 * c1 * (float)ENT_DIM + q1[4]
                        + 2.0f * (a1 * c1 * q1[1] + a1 * q1[2] + c1 * q1[3]);
        ((float2*)out)[g] = make_float2(sc0, sc1);
    } else {
        const int hi = hidx[b0], ti = tidx[b0], ri = ridx[b0];
        const float2 hs = hstats[hi];
        const float2 ts = tstats[ti];
        const float c = hs.x - ts.x, a = hs.y - ts.y;
        const float* q = rs + ri * 9;
        out[b0] = a * a * q[0] + c * c * (float)ENT_DIM + q[4]
                + 2.0f * (a * c * q[1] + a * q[2] + c * q[3]);
    }
}

// Fallback (only if ws_size is too small): direct wave-per-element compute.
__global__ void direct_kernel(const float* __restrict__ he, const float* __restrict__ hep,
                              const float* __restrict__ te, const float* __restrict__ tep,
                              const float* __restrict__ re, const float* __restrict__ rep,
                              const int* __restrict__ hidx, const int* __restrict__ tidx,
                              const int* __restrict__ ridx,
                              float* __restrict__ out, int B) {
    const int wave = (blockIdx.x * blockDim.x + threadIdx.x) >> 6;
    const int lane = threadIdx.x & 63;
    if (wave >= B) return;
    const int hi = hidx[wave], ti = tidx[wave], ri = ridx[wave];
    const float2 h  = ((const float2*)(he  + (size_t)hi * ENT_DIM))[lane];
    const float2 hp = ((const float2*)(hep + (size_t)hi * ENT_DIM))[lane];
    const float2 t  = ((const float2*)(te  + (size_t)ti * ENT_DIM))[lane];
    const float2 tp = ((const float2*)(tep + (size_t)ti * ENT_DIM))[lane];
    const float2 r  = ((const float2*)(re  + (size_t)ri * ENT_DIM))[lane];
    const float2 rp = ((const float2*)(rep + (size_t)ri * ENT_DIM))[lane];
    float hd = h.x * hp.x + h.y * hp.y;
    float hs = h.x + h.y;
    float td = t.x * tp.x + t.y * tp.y;
    float ts = t.x + t.y;
    #pragma unroll
    for (int off = 32; off >= 1; off >>= 1) {
        hd += __shfl_xor(hd, off, 64);
        hs += __shfl_xor(hs, off, 64);
        td += __shfl_xor(td, off, 64);
        ts += __shfl_xor(ts, off, 64);
    }
    const float a = hd - td, c = hs - ts;
    const float dx = a * rp.x + c + r.x;
    const float dy = a * rp.y + c + r.y;
    float sc = dx * dx + dy * dy;
    #pragma unroll
    for (int off = 32; off >= 1; off >>= 1) sc += __shfl_xor(sc, off, 64);
    if (lane == 0) out[wave] = sc;
}

extern "C" void kernel_launch(void* const* d_in, const int* in_sizes, int n_in,
                              void* d_out, int out_size, void* d_ws, size_t ws_size,
                              hipStream_t stream) {
    const float* he  = (const float*)d_in[0];
    const float* hep = (const float*)d_in[1];
    const float* te  = (const float*)d_in[2];
    const float* tep = (const float*)d_in[3];
    const float* re  = (const float*)d_in[4];
    const float* rep = (const float*)d_in[5];
    const int* hidx  = (const int*)d_in[6];
    const int* tidx  = (const int*)d_in[7];
    const int* ridx  = (const int*)d_in[8];
    float* out = (float*)d_out;

    const int n_nodes = in_sizes[0] / ENT_DIM;   // 200000
    const int n_rels  = in_sizes[4] / ENT_DIM;   // 500
    const int B       = in_sizes[6];             // 500000

    const size_t hstats_bytes = (size_t)n_nodes * sizeof(float2);
    const size_t rstats_bytes = (size_t)n_rels * 8 * sizeof(float);
    const size_t need = 2 * hstats_bytes + rstats_bytes;
    const size_t lds_bytes = (size_t)n_rels * 9 * sizeof(float);

    if (ws_size >= need && lds_bytes <= 60 * 1024) {
        float2* hstats = (float2*)d_ws;
        float2* tstats = (float2*)((char*)d_ws + hstats_bytes);
        float*  rstats = (float*)((char*)d_ws + 2 * hstats_bytes);

        // Pass 1: 2*n_nodes rows, 2 rows/wave, 4 waves/block.
        const int waves1  = n_nodes;                  // (2*n_nodes jobs)/2
        const int blocks1 = (waves1 + 3) / 4;
        node_stats_kernel<<<blocks1, 256, 0, stream>>>(he, hep, te, tep,
                                                       hstats, tstats, n_nodes);
        // Pass 2
        const int blocks2 = (n_rels * 64 + 255) / 256;
        rel_stats_kernel<<<blocks2, 256, 0, stream>>>(re, rep, rstats, n_rels);
        // Pass 3: 2 elements per thread.
        const int nthreads = (B + 1) / 2;
        const int blocks3  = (nthreads + 255) / 256;
        score_kernel<<<blocks3, 256, lds_bytes, stream>>>(hidx, tidx, ridx,
                                                          hstats, tstats, rstats,
                                                          out, B, n_rels);
    } else {
        const int blocks = (B * 64 + 255) / 256;
        direct_kernel<<<blocks, 256, 0, stream>>>(he, hep, te, tep, re, rep,
                                                  hidx, tidx, ridx, out, B);
    }
}